// Round 5
// baseline (391.876 us; speedup 1.0000x reference)
//
#include <hip/hip_runtime.h>

#define NTHREADS 256

// problem constants
constexpr int Cc   = 32;
constexpr int Hh   = 256;
constexpr int R1c  = 2048;
constexpr int R2c  = 2624;
constexpr float EPSc = 1e-5f;

// ws float offsets (stats)
constexpr int SLOTS1  = 0;
constexpr int SLOTS1Q = 4096;
constexpr int SLOTS2  = 8192;
constexpr int SLOTS2Q = 12288;
constexpr int SLOTS3  = 16384;
constexpr int SLOTS3Q = 18432;
constexpr int FIN1    = 20480;
constexpr int FIN2    = 20608;
constexpr int FIN3    = 20736;
constexpr int STATS_ZERO_FLOATS = 20480;

// byte offsets in ws
constexpr size_t ST2_OFF = 131072;                       // bf16 transposed s
constexpr size_t ST2_BYTES = 8ull * 1024 * 4672 * 2;     // 76,546,048
constexpr size_t ZB_OFF  = ST2_OFF + ST2_BYTES;          // 76,677,120
constexpr size_t ZB_BYTES = 8192ull * 4096 * 2;          // 67,108,864
constexpr size_t OB_OFF  = ZB_OFF + ZB_BYTES;            // 143,785,984
constexpr size_t OB_BYTES = 8192ull * 2048 * 2;          // 33,554,432

// ---- bf16 helpers -------------------------------------------------------
__device__ __forceinline__ ushort f_to_bf16(float f) {
    union { float f; unsigned int i; } v; v.f = f;
    unsigned int r = (v.i + 0x7fffu + ((v.i >> 16) & 1u)) >> 16;
    return (ushort)r;
}
__device__ __forceinline__ float bf16lo_to_f(unsigned int u) {
    union { unsigned int i; float f; } v; v.i = u << 16; return v.f;
}
__device__ __forceinline__ float bf16hi_to_f(unsigned int u) {
    union { unsigned int i; float f; } v; v.i = u & 0xffff0000u; return v.f;
}
__device__ __forceinline__ unsigned int pack_bf16(float lo, float hi) {
    return (unsigned int)f_to_bf16(lo) | ((unsigned int)f_to_bf16(hi) << 16);
}

// MFMA frag types (per guide: 8 bf16 in 4 VGPRs as short8; 4 f32 acc)
typedef short bf16x8 __attribute__((ext_vector_type(8)));
typedef float f32x4  __attribute__((ext_vector_type(4)));

__device__ __forceinline__ f32x4 mfma16(bf16x8 a, bf16x8 b, f32x4 c) {
    return __builtin_amdgcn_mfma_f32_16x16x32_bf16(a, b, c, 0, 0, 0);
}

// ---------------------------------------------------------------------------
// Transpose s [8][4672][1024] fp32 -> st bf16 [8][1024][4672], packed uint writes.
__global__ __launch_bounds__(256)
void transpose_s_bf16p(const float* __restrict__ s, ushort* __restrict__ st) {
    __shared__ float tile[64][33];
    const int bi = blockIdx.z;
    const int p0 = blockIdx.x * 64;   // 4672 = 73*64
    const int q0 = blockIdx.y * 32;   // 1024 = 32*32
    const int tx = threadIdx.x, ty = threadIdx.y;   // 32 x 8
    const float* sb = s + (size_t)bi * 4672 * 1024;
    #pragma unroll
    for (int r = ty; r < 64; r += 8)
        tile[r][tx] = sb[(size_t)(p0 + r) * 1024 + q0 + tx];
    __syncthreads();
    unsigned int* stu = (unsigned int*)(st + (size_t)bi * 1024 * 4672);
    #pragma unroll
    for (int rr = ty; rr < 32; rr += 8) {
        int q = q0 + rr;
        unsigned int v = pack_bf16(tile[2*tx][rr], tile[2*tx + 1][rr]);
        stu[((size_t)q * 4672 + p0) / 2 + tx] = v;
    }
}

// ---------------------------------------------------------------------------
// K1: MFMA stage-1 (y = w1*x), stats1 only. Frag layouts:
//  A: lane holds A[row=lane&15][k=(lane>>4)*8+j]; B: B[k=(lane>>4)*8+j][col=lane&15]
//  C: col=lane&15, row=(lane>>4)*4+reg   [verified layout, learn_hip m89]
__global__ __launch_bounds__(NTHREADS)
void k1_mfma(const float* __restrict__ x, const ushort* __restrict__ st,
             float* __restrict__ ws) {
    __shared__ __align__(16) ushort frA[2048];   // 4 mtiles * 64 lanes * 8
    __shared__ __align__(16) ushort frB[3584];   // 7 ntiles * 64 lanes * 8
    const int t = threadIdx.x, blk = blockIdx.x;
    const int bi = blk >> 10, f = (blk >> 5) & 31, g = blk & 31, slot = blk & 63;

    const ushort* wp = st + (size_t)(bi * 1024 + f * 32 + g) * 4672;
    {   // w1[ch][c] -> A frags: one uint4 (8 bf16, consec c) = one lane-frag
        uint4 v = ((const uint4*)wp)[t];
        int ch = t >> 2, kb = t & 3;
        ((uint4*)frA)[(ch >> 4) * 64 + (kb << 4) + (ch & 15)] = v;
    }
    // x patch (reflect halo) -> B frags bf16, px padded to 112 with zeros
    const float* xb = x + (size_t)bi * Cc * Hh * Hh;
    for (int i = t; i < 3584; i += NTHREADS) {
        int c = i / 112, px = i - c * 112;
        ushort val = 0;
        if (px < 100) {
            int pr = px / 10, pc = px - pr * 10;
            int row = f * 8 - 1 + pr; row = row < 0 ? -row : (row > 255 ? 510 - row : row);
            int col = g * 8 - 1 + pc; col = col < 0 ? -col : (col > 255 ? 510 - col : col);
            val = f_to_bf16(xb[(size_t)c * 65536 + row * 256 + col]);
        }
        frB[((px >> 4) * 64 + (((c >> 3) & 3) << 4) + (px & 15)) * 8 + (c & 7)] = val;
    }
    __syncthreads();

    const int wid = t >> 6, lane = t & 63;
    bf16x8 a = ((const bf16x8*)frA)[wid * 64 + lane];
    f32x4 acc[7];
    #pragma unroll
    for (int n = 0; n < 7; n++) {
        f32x4 z = {0.f, 0.f, 0.f, 0.f};
        bf16x8 b = ((const bf16x8*)frB)[n * 64 + lane];
        acc[n] = mfma16(a, b, z);
    }
    // stats1: zero-padded px contribute 0 to sum and sumsq
    float s4[4] = {0.f,0.f,0.f,0.f}, q4[4] = {0.f,0.f,0.f,0.f};
    #pragma unroll
    for (int n = 0; n < 7; n++)
        #pragma unroll
        for (int r = 0; r < 4; r++) { float v = acc[n][r]; s4[r] += v; q4[r] += v * v; }
    #pragma unroll
    for (int r = 0; r < 4; r++) {
        #pragma unroll
        for (int m = 1; m <= 8; m <<= 1) {
            s4[r] += __shfl_xor(s4[r], m);
            q4[r] += __shfl_xor(q4[r], m);
        }
    }
    if ((lane & 15) == 0) {
        #pragma unroll
        for (int r = 0; r < 4; r++) {
            int ch = wid * 16 + (lane >> 4) * 4 + r;
            atomicAdd(&ws[SLOTS1  + ch * 64 + slot], s4[r]);
            atomicAdd(&ws[SLOTS1Q + ch * 64 + slot], q4[r]);
        }
    }
}

// ---------------------------------------------------------------------------
// K2: recompute stage-1 via MFMA, BN1+relu6, y->LDS bf16 [ch][100],
//     depthwise 3x3, stats2, store z bf16.
__global__ __launch_bounds__(NTHREADS)
void k2_mfma(const float* __restrict__ x, const ushort* __restrict__ st,
             ushort* __restrict__ zbuf, float* __restrict__ ws) {
    __shared__ __align__(16) ushort frA[2048];
    __shared__ __align__(16) ushort frBy[6400];   // B frags [0,3584); y overlays [0,6400)
    __shared__ float w2s[576];
    __shared__ float fin_s[128];
    const int t = threadIdx.x, blk = blockIdx.x;
    const int bi = blk >> 10, f = (blk >> 5) & 31, g = blk & 31, slot = blk & 63;

    const ushort* wp = st + (size_t)(bi * 1024 + f * 32 + g) * 4672;
    {
        uint4 v = ((const uint4*)wp)[t];
        int ch = t >> 2, kb = t & 3;
        ((uint4*)frA)[(ch >> 4) * 64 + (kb << 4) + (ch & 15)] = v;
    }
    {
        const unsigned int* w2u = (const unsigned int*)(wp + R1c);
        for (int i = t; i < 288; i += NTHREADS) {
            unsigned int u = w2u[i];
            w2s[2*i]   = bf16lo_to_f(u);
            w2s[2*i+1] = bf16hi_to_f(u);
        }
    }
    if (t < 128) fin_s[t] = ws[FIN1 + t];
    const float* xb = x + (size_t)bi * Cc * Hh * Hh;
    for (int i = t; i < 3584; i += NTHREADS) {
        int c = i / 112, px = i - c * 112;
        ushort val = 0;
        if (px < 100) {
            int pr = px / 10, pc = px - pr * 10;
            int row = f * 8 - 1 + pr; row = row < 0 ? -row : (row > 255 ? 510 - row : row);
            int col = g * 8 - 1 + pc; col = col < 0 ? -col : (col > 255 ? 510 - col : col);
            val = f_to_bf16(xb[(size_t)c * 65536 + row * 256 + col]);
        }
        frBy[((px >> 4) * 64 + (((c >> 3) & 3) << 4) + (px & 15)) * 8 + (c & 7)] = val;
    }
    __syncthreads();

    const int wid = t >> 6, lane = t & 63;
    bf16x8 a = ((const bf16x8*)frA)[wid * 64 + lane];
    f32x4 acc[7];
    #pragma unroll
    for (int n = 0; n < 7; n++) {
        f32x4 z = {0.f, 0.f, 0.f, 0.f};
        bf16x8 b = ((const bf16x8*)frBy)[n * 64 + lane];
        acc[n] = mfma16(a, b, z);
    }
    __syncthreads();   // all B-frag reads done; safe to overlay y

    // BN1 + relu6 -> y bf16 [ch][100]
    #pragma unroll
    for (int n = 0; n < 7; n++) {
        int px = n * 16 + (lane & 15);
        if (px < 100) {
            #pragma unroll
            for (int r = 0; r < 4; r++) {
                int ch = wid * 16 + (lane >> 4) * 4 + r;
                float v = fminf(fmaxf(acc[n][r] * fin_s[ch] + fin_s[64 + ch], 0.f), 6.f);
                frBy[ch * 100 + px] = f_to_bf16(v);
            }
        }
    }
    __syncthreads();

    // depthwise 3x3 valid
    const int ch2 = t >> 2, quad = t & 3, p0 = quad * 2;
    const unsigned int* yu = (const unsigned int*)frBy;
    float yr[4][10];
    #pragma unroll
    for (int r = 0; r < 4; r++) {
        int base = ch2 * 50 + (p0 + r) * 5;
        #pragma unroll
        for (int k = 0; k < 5; k++) {
            unsigned int u = yu[base + k];
            yr[r][2*k]   = bf16lo_to_f(u);
            yr[r][2*k+1] = bf16hi_to_f(u);
        }
    }
    float zacc[2][8];
    #pragma unroll
    for (int pr = 0; pr < 2; pr++)
        #pragma unroll
        for (int q = 0; q < 8; q++) zacc[pr][q] = 0.f;
    #pragma unroll
    for (int du = 0; du < 3; du++)
        #pragma unroll
        for (int dv = 0; dv < 3; dv++) {
            float wv = w2s[ch2 * 9 + du * 3 + dv];
            #pragma unroll
            for (int pr = 0; pr < 2; pr++)
                #pragma unroll
                for (int q = 0; q < 8; q++)
                    zacc[pr][q] += wv * yr[pr + du][q + dv];
        }
    // stats2
    float zs = 0.f, zq = 0.f;
    #pragma unroll
    for (int pr = 0; pr < 2; pr++)
        #pragma unroll
        for (int q = 0; q < 8; q++) { float v = zacc[pr][q]; zs += v; zq += v * v; }
    zs += __shfl_xor(zs, 1); zs += __shfl_xor(zs, 2);
    zq += __shfl_xor(zq, 1); zq += __shfl_xor(zq, 2);
    if (quad == 0) {
        atomicAdd(&ws[SLOTS2  + ch2 * 64 + slot], zs);
        atomicAdd(&ws[SLOTS2Q + ch2 * 64 + slot], zq);
    }
    // store raw z bf16 [64][64]
    ushort* zp = zbuf + (size_t)blk * 4096;
    #pragma unroll
    for (int pr = 0; pr < 2; pr++) {
        uint4 pk;
        pk.x = pack_bf16(zacc[pr][0], zacc[pr][1]);
        pk.y = pack_bf16(zacc[pr][2], zacc[pr][3]);
        pk.z = pack_bf16(zacc[pr][4], zacc[pr][5]);
        pk.w = pack_bf16(zacc[pr][6], zacc[pr][7]);
        *(uint4*)(zp + ch2 * 64 + (p0 + pr) * 8) = pk;
    }
}

// ---------------------------------------------------------------------------
// K3: z bf16 -> BN2+relu6 -> MFMA stage-3 (M=32,N=64,K=64), stats3, store o bf16.
__global__ __launch_bounds__(NTHREADS)
void k3_mfma(const ushort* __restrict__ zbuf, const ushort* __restrict__ st,
             ushort* __restrict__ obuf, float* __restrict__ ws) {
    __shared__ __align__(16) ushort frA[2048];   // 2 m * 2 k * 64 * 8
    __shared__ __align__(16) ushort frB[4096];   // 2 k * 4 n * 64 * 8
    __shared__ __align__(16) ushort o_lds[2048]; // [32 oc][64 px]
    __shared__ float fin2[128];
    const int t = threadIdx.x, blk = blockIdx.x;
    const int bi = blk >> 10, f = (blk >> 5) & 31, g = blk & 31, slot = blk & 63;

    if (t < 128) fin2[t] = ws[FIN2 + t];
    const ushort* wp = st + (size_t)(bi * 1024 + f * 32 + g) * 4672;
    {   // w3[oc][ch] -> A frags
        uint4 v = ((const uint4*)(wp + R2c))[t];
        int oc = t >> 3, kb8 = t & 7;
        int kstep = kb8 >> 2, kb = kb8 & 3;
        ((uint4*)frA)[((oc >> 4) * 2 + kstep) * 64 + (kb << 4) + (oc & 15)] = v;
    }
    __syncthreads();   // fin2 ready before z staging

    const uint4* zsrc = (const uint4*)(zbuf + (size_t)blk * 4096);
    for (int i = t; i < 512; i += NTHREADS) {
        uint4 v = zsrc[i];
        int ch = i >> 3, px0 = (i & 7) * 8;
        float a2 = fin2[ch], b2 = fin2[64 + ch];
        int base = (ch >> 5) << 2;       // kstep*4
        int kb = (ch >> 3) & 3, j = ch & 7;
        unsigned int uu[4] = {v.x, v.y, v.z, v.w};
        #pragma unroll
        for (int q = 0; q < 4; q++) {
            float lo = fminf(fmaxf(bf16lo_to_f(uu[q]) * a2 + b2, 0.f), 6.f);
            float hi = fminf(fmaxf(bf16hi_to_f(uu[q]) * a2 + b2, 0.f), 6.f);
            int px = px0 + 2 * q;
            frB[((base + (px >> 4)) * 64 + (kb << 4) + (px & 15)) * 8 + j] = f_to_bf16(lo);
            px++;
            frB[((base + (px >> 4)) * 64 + (kb << 4) + (px & 15)) * 8 + j] = f_to_bf16(hi);
        }
    }
    __syncthreads();

    const int wid = t >> 6, lane = t & 63;
    const int m = wid >> 1, nb = (wid & 1) * 2;
    f32x4 acc[2];
    #pragma unroll
    for (int nn = 0; nn < 2; nn++) {
        f32x4 c = {0.f, 0.f, 0.f, 0.f};
        #pragma unroll
        for (int s = 0; s < 2; s++) {
            bf16x8 a = ((const bf16x8*)frA)[(m * 2 + s) * 64 + lane];
            bf16x8 b = ((const bf16x8*)frB)[(s * 4 + nb + nn) * 64 + lane];
            c = mfma16(a, b, c);
        }
        acc[nn] = c;
    }
    // stats3 + o pack
    float s4[4] = {0.f,0.f,0.f,0.f}, q4[4] = {0.f,0.f,0.f,0.f};
    #pragma unroll
    for (int nn = 0; nn < 2; nn++)
        #pragma unroll
        for (int r = 0; r < 4; r++) {
            float v = acc[nn][r];
            s4[r] += v; q4[r] += v * v;
            o_lds[(m * 16 + (lane >> 4) * 4 + r) * 64 + (nb + nn) * 16 + (lane & 15)] = f_to_bf16(v);
        }
    #pragma unroll
    for (int r = 0; r < 4; r++) {
        #pragma unroll
        for (int mm = 1; mm <= 8; mm <<= 1) {
            s4[r] += __shfl_xor(s4[r], mm);
            q4[r] += __shfl_xor(q4[r], mm);
        }
    }
    if ((lane & 15) == 0) {
        #pragma unroll
        for (int r = 0; r < 4; r++) {
            int oc = m * 16 + (lane >> 4) * 4 + r;
            atomicAdd(&ws[SLOTS3  + oc * 64 + slot], s4[r]);
            atomicAdd(&ws[SLOTS3Q + oc * 64 + slot], q4[r]);
        }
    }
    __syncthreads();
    ushort* op = obuf + (size_t)blk * 2048;
    ((uint4*)op)[t] = ((const uint4*)o_lds)[t];   // 256 uint4 = 2048 bf16
}

// ---------------------------------------------------------------------------
// K4: out = x + bn3(o), vectorized x4.
__global__ __launch_bounds__(NTHREADS)
void k4_read4(const float* __restrict__ x, const float* __restrict__ ws,
              const ushort* __restrict__ obuf, float* __restrict__ out) {
    size_t idx = (size_t)blockIdx.x * NTHREADS + threadIdx.x;
    size_t e = idx * 4;
    int wq = (int)(e & 255);
    int h  = (int)((e >> 8) & 255);
    int oc = (int)((e >> 16) & 31);
    int bi = (int)(e >> 21);
    float a3 = ws[FIN3 + oc], b3c = ws[FIN3 + 32 + oc];
    int blk = (bi << 10) | ((h >> 3) << 5) | (wq >> 3);
    int pix = ((h & 7) << 3) | (wq & 7);
    uint2 ov = *(const uint2*)(obuf + (size_t)blk * 2048 + oc * 64 + pix);
    float4 xv = *(const float4*)(x + e);
    float4 r;
    r.x = xv.x + bf16lo_to_f(ov.x) * a3 + b3c;
    r.y = xv.y + bf16hi_to_f(ov.x) * a3 + b3c;
    r.z = xv.z + bf16lo_to_f(ov.y) * a3 + b3c;
    r.w = xv.w + bf16hi_to_f(ov.y) * a3 + b3c;
    *(float4*)(out + e) = r;
}

__global__ void finalize_k(float* __restrict__ ws, int stage,
                           const float* __restrict__ gamma, const float* __restrict__ beta) {
    int ch = threadIdx.x;
    int nch = (stage == 3) ? 32 : 64;
    if (ch >= nch) return;
    int so = (stage == 1) ? SLOTS1  : (stage == 2) ? SLOTS2  : SLOTS3;
    int sq = (stage == 1) ? SLOTS1Q : (stage == 2) ? SLOTS2Q : SLOTS3Q;
    int fo = (stage == 1) ? FIN1    : (stage == 2) ? FIN2    : FIN3;
    float N = (stage == 1) ? 819200.0f : 524288.0f;
    float sm = 0.f, qq = 0.f;
    for (int j = 0; j < 64; j++) { sm += ws[so + ch*64 + j]; qq += ws[sq + ch*64 + j]; }
    float mean = sm / N;
    float var  = qq / N - mean * mean;
    float rstd = rsqrtf(var + EPSc);
    float a = rstd * gamma[ch];
    ws[fo + ch]       = a;
    ws[fo + nch + ch] = beta[ch] - mean * a;
}

// ---------------------------------------------------------------------------
extern "C" void kernel_launch(void* const* d_in, const int* in_sizes, int n_in,
                              void* d_out, int out_size, void* d_ws, size_t ws_size,
                              hipStream_t stream) {
    const float* x  = (const float*)d_in[0];
    const float* s  = (const float*)d_in[1];
    const float* g1 = (const float*)d_in[2];
    const float* b1 = (const float*)d_in[3];
    const float* g2 = (const float*)d_in[4];
    const float* b2 = (const float*)d_in[5];
    const float* g3 = (const float*)d_in[6];
    const float* b3 = (const float*)d_in[7];
    float* out = (float*)d_out;
    float* ws  = (float*)d_ws;

    hipMemsetAsync(d_ws, 0, STATS_ZERO_FLOATS * sizeof(float), stream);

    ushort* st2 = (ushort*)((char*)d_ws + ST2_OFF);
    ushort* zb  = (ushort*)((char*)d_ws + ZB_OFF);
    ushort* ob  = (ushort*)((char*)d_ws + OB_OFF);

    transpose_s_bf16p<<<dim3(73, 32, 8), dim3(32, 8), 0, stream>>>(s, st2);
    k1_mfma<<<8192, NTHREADS, 0, stream>>>(x, st2, ws);
    finalize_k<<<1, 64, 0, stream>>>(ws, 1, g1, b1);
    k2_mfma<<<8192, NTHREADS, 0, stream>>>(x, st2, zb, ws);
    finalize_k<<<1, 64, 0, stream>>>(ws, 2, g2, b2);
    k3_mfma<<<8192, NTHREADS, 0, stream>>>(zb, st2, ob, ws);
    finalize_k<<<1, 64, 0, stream>>>(ws, 3, g3, b3);
    k4_read4<<<16384, NTHREADS, 0, stream>>>(x, ws, ob, out);
}